// Round 11
// baseline (66.669 us; speedup 1.0000x reference)
//
#include <hip/hip_runtime.h>

#define LN 63
#define BATCHN 16384

typedef __attribute__((ext_vector_type(8))) short bf16x8;   // 8 bf16 in 4 VGPRs
typedef __attribute__((ext_vector_type(4))) float f32x4;

__device__ __forceinline__ float fast_exp(float v) {
    return __builtin_amdgcn_exp2f(v * 1.4426950408889634f);
}
__device__ __forceinline__ float fast_tanh(float v) {
    float e = __builtin_amdgcn_exp2f(v * 2.8853900817779268f); // e^{2v}
    return 1.0f - 2.0f * __builtin_amdgcn_rcpf(e + 1.0f);
}
__device__ __forceinline__ short f2bf(float f) {
    __bf16 h = (__bf16)f;
    return __builtin_bit_cast(short, h);
}
__device__ __forceinline__ unsigned int pk2(float a, float b) {
    return (unsigned int)(unsigned short)f2bf(a) |
           ((unsigned int)(unsigned short)f2bf(b) << 16);
}

// kappa j-index for W2/W3 fragment element e (derived from R6's verified LDS
// reads): e<4 -> 32s+4g+e ; e>=4 -> 32s+16+4g+(e-4).
__device__ __forceinline__ int kappa_j(int s, int g, int e) {
    return (e < 4) ? (32 * s + 4 * g + e) : (32 * s + 16 + 4 * g + e - 4);
}

// Combined prep: blocks 0..62 write per-lane fragment-ordered bf16 weights
// into Afrag[l] (18432 B per l); blocks 63.. convert x -> xbf.  (R9-verified)
__global__ __launch_bounds__(256) void prep_kernel(
    const float* __restrict__ x,
    const float* __restrict__ W1, const float* __restrict__ b1,
    const float* __restrict__ W2, const float* __restrict__ W3,
    unsigned short* __restrict__ Afrag,
    unsigned short* __restrict__ xbf)
{
    const int t = threadIdx.x;
    const int b = blockIdx.x;
    if (b >= LN) {
        const int i = ((b - LN) * 256 + t) * 4;
        const float4 v = *reinterpret_cast<const float4*>(x + i);
        ushort4 o;
        o.x = (unsigned short)f2bf(v.x);
        o.y = (unsigned short)f2bf(v.y);
        o.z = (unsigned short)f2bf(v.z);
        o.w = (unsigned short)f2bf(v.w);
        *reinterpret_cast<ushort4*>(xbf + i) = o;
        return;
    }
    const int l = b;
    unsigned short* Af = Afrag + (size_t)l * 9216;

    // A1: 512 items (s,tt,lane), 2 per thread
    #pragma unroll
    for (int it = 0; it < 2; ++it) {
        const int item = t + it * 256;
        const int s = item >> 8, tt = (item >> 6) & 3, lane = item & 63;
        const int g = lane >> 4, mcol = lane & 15, h = 16 * tt + mcol;
        unsigned pk[4];
        #pragma unroll
        for (int ep = 0; ep < 4; ++ep) {
            float v[2];
            #pragma unroll
            for (int k = 0; k < 2; ++k) {
                const int e = 2 * ep + k;
                const int j = 32 * s + 8 * g + e;
                float val;
                if (j == 63)      val = b1[l * 64 + h];
                else if (j <= l)  val = W1[(l * LN + j) * 64 + h];
                else              val = 0.0f;
                v[k] = val;
            }
            pk[ep] = pk2(v[0], v[1]);
        }
        *reinterpret_cast<uint4*>(Af + ((size_t)item) * 8) =
            uint4{pk[0], pk[1], pk[2], pk[3]};
    }
    // A2: 512 items
    #pragma unroll
    for (int it = 0; it < 2; ++it) {
        const int item = t + it * 256;
        const int s = item >> 8, tt = (item >> 6) & 3, lane = item & 63;
        const int g = lane >> 4, mcol = lane & 15, h = 16 * tt + mcol;
        unsigned pk[4];
        #pragma unroll
        for (int ep = 0; ep < 4; ++ep) {
            float v[2];
            #pragma unroll
            for (int k = 0; k < 2; ++k) {
                const int e = 2 * ep + k;
                v[k] = W2[(l * 64 + kappa_j(s, g, e)) * 64 + h];
            }
            pk[ep] = pk2(v[0], v[1]);
        }
        *reinterpret_cast<uint4*>(Af + 4096 + ((size_t)item) * 8) =
            uint4{pk[0], pk[1], pk[2], pk[3]};
    }
    // A3: 128 items (s,lane)
    if (t < 128) {
        const int s = t >> 6, lane = t & 63;
        const int g = lane >> 4, mcol = lane & 15;
        unsigned pk[4] = {0u, 0u, 0u, 0u};
        if (mcol < 2) {
            #pragma unroll
            for (int ep = 0; ep < 4; ++ep) {
                float v[2];
                #pragma unroll
                for (int k = 0; k < 2; ++k) {
                    const int e = 2 * ep + k;
                    v[k] = W3[(l * 64 + kappa_j(s, g, e)) * 2 + mcol];
                }
                pk[ep] = pk2(v[0], v[1]);
            }
        }
        *reinterpret_cast<uint4*>(Af + 8192 + ((size_t)t) * 8) =
            uint4{pk[0], pk[1], pk[2], pk[3]};
    }
}

// Block = one l (0..62) x 1024 batch rows. Grid 63*16 = 1008. No LDS.
// R10: register diet for occupancy 2->3 waves/SIMD. (a) grp loop NOT unrolled
// (unroll-2 doubled transients); (b) w1f fragments are re-loaded EVERY grp via
// volatile asm global_load_dwordx4 (L1-resident: same addr all grps, wave-
// uniform across the block's 4 waves) -> 32 fewer persistent regs. w2f/w3f/
// bias2 stay pinned. Rule-18: waitcnt vmcnt(0) + sched_barrier(0) before use.
// Register contents identical to R9 (verified absmax 0.0625).
template<int XBF>
__global__ __launch_bounds__(256, 2) void maf_main_kernel(
    const float* __restrict__ x,
    const unsigned short* __restrict__ xbf,
    const unsigned short* __restrict__ Afrag,
    const float* __restrict__ b2,
    const float* __restrict__ b3,
    float* __restrict__ zT,   // ws: [63][BATCH] row cr=62-l (z col l+1 reversed)
    float* __restrict__ aT)   // ws: [63][BATCH] alpha col l+1
{
    const int t = threadIdx.x;
    const int bid = blockIdx.x;
    const int l = bid % LN;                 // block-uniform
    const int rowBase = (bid / LN) * 1024;

    const int lane = t & 63;
    const int w = t >> 6;
    const int g = lane >> 4;
    const int mcol = lane & 15;

    // ---------------- persistent A-fragments: W2, W3 (+pin) ----------------
    const unsigned short* Af = Afrag + (size_t)l * 9216;
    bf16x8 w2f[2][4], w3f[2];
    #pragma unroll
    for (int s = 0; s < 2; ++s) {
        #pragma unroll
        for (int tt = 0; tt < 4; ++tt)
            w2f[s][tt] = *reinterpret_cast<const bf16x8*>(Af + 4096 + ((s * 4 + tt) * 64 + lane) * 8);
        w3f[s] = *reinterpret_cast<const bf16x8*>(Af + 8192 + (s * 64 + lane) * 8);
    }
    f32x4 bias2[4];
    #pragma unroll
    for (int tt = 0; tt < 4; ++tt) {
        const float4 v2 = *reinterpret_cast<const float4*>(&b2[l * 64 + 16 * tt + 4 * g]);
        bias2[tt] = f32x4{v2.x, v2.y, v2.z, v2.w};
    }
    #pragma unroll
    for (int s = 0; s < 2; ++s) {
        #pragma unroll
        for (int tt = 0; tt < 4; ++tt) asm volatile("" : "+v"(w2f[s][tt]));
        asm volatile("" : "+v"(w3f[s]));
    }
    #pragma unroll
    for (int tt = 0; tt < 4; ++tt) asm volatile("" : "+v"(bias2[tt]));

    const float b30 = b3[l * 2 + 0];
    const float b31 = b3[l * 2 + 1];
    const short one_bf = (short)0x3F80;   // bf16(1.0)

    // w1f load bases: A1 fragment (s,tt) at byte (s*4+tt)*1024 + lane*16
    const unsigned long long a0 = (unsigned long long)(uintptr_t)Af + (unsigned)lane * 16u;
    const unsigned long long a1 = a0 + 4096u;

    // ---------------- 16 groups of 16 rows per wave ----------------
    #pragma unroll 1
    for (int grp = 0; grp < 16; ++grp) {
        const int row = rowBase + w * 256 + grp * 16 + mcol;

        // w1f: 8 x 16B from L1 (same addr every grp; volatile -> stays in-loop)
        bf16x8 w1f0, w1f1, w1f2, w1f3, w1f4, w1f5, w1f6, w1f7;
        asm volatile("global_load_dwordx4 %0, %1, off"             : "=v"(w1f0) : "v"(a0) : "memory");
        asm volatile("global_load_dwordx4 %0, %1, off offset:1024" : "=v"(w1f1) : "v"(a0) : "memory");
        asm volatile("global_load_dwordx4 %0, %1, off offset:2048" : "=v"(w1f2) : "v"(a0) : "memory");
        asm volatile("global_load_dwordx4 %0, %1, off offset:3072" : "=v"(w1f3) : "v"(a0) : "memory");
        asm volatile("global_load_dwordx4 %0, %1, off"             : "=v"(w1f4) : "v"(a1) : "memory");
        asm volatile("global_load_dwordx4 %0, %1, off offset:1024" : "=v"(w1f5) : "v"(a1) : "memory");
        asm volatile("global_load_dwordx4 %0, %1, off offset:2048" : "=v"(w1f6) : "v"(a1) : "memory");
        asm volatile("global_load_dwordx4 %0, %1, off offset:3072" : "=v"(w1f7) : "v"(a1) : "memory");

        bf16x8 xf[2];
        if constexpr (XBF) {
            xf[0] = *reinterpret_cast<const bf16x8*>(xbf + (size_t)row * 64 + 8 * g);
            xf[1] = *reinterpret_cast<const bf16x8*>(xbf + (size_t)row * 64 + 32 + 8 * g);
        } else {
            const float* xr = x + (size_t)row * 64;
            #pragma unroll
            for (int s = 0; s < 2; ++s) {
                const float4 a = *reinterpret_cast<const float4*>(xr + 32 * s + 8 * g);
                const float4 b = *reinterpret_cast<const float4*>(xr + 32 * s + 8 * g + 4);
                bf16x8 f;
                f[0] = f2bf(a.x); f[1] = f2bf(a.y); f[2] = f2bf(a.z); f[3] = f2bf(a.w);
                f[4] = f2bf(b.x); f[5] = f2bf(b.y); f[6] = f2bf(b.z); f[7] = f2bf(b.w);
                xf[s] = f;
            }
        }
        // k-slot 63 pairs with the b1 row staged in A1: force to 1.0
        if (g == 3) xf[1][7] = one_bf;

        // all loads (asm w1f + compiler xf) drained before MFMA consumes them
        asm volatile("s_waitcnt vmcnt(0)" ::: "memory");
        __builtin_amdgcn_sched_barrier(0);   // rule 18: no MFMA hoist above

        // layer 1 (bias via k-slot 63)
        f32x4 c1[4];
        #pragma unroll
        for (int tt = 0; tt < 4; ++tt) c1[tt] = f32x4{0.0f, 0.0f, 0.0f, 0.0f};
        c1[0] = __builtin_amdgcn_mfma_f32_16x16x32_bf16(w1f0, xf[0], c1[0], 0, 0, 0);
        c1[1] = __builtin_amdgcn_mfma_f32_16x16x32_bf16(w1f1, xf[0], c1[1], 0, 0, 0);
        c1[2] = __builtin_amdgcn_mfma_f32_16x16x32_bf16(w1f2, xf[0], c1[2], 0, 0, 0);
        c1[3] = __builtin_amdgcn_mfma_f32_16x16x32_bf16(w1f3, xf[0], c1[3], 0, 0, 0);
        c1[0] = __builtin_amdgcn_mfma_f32_16x16x32_bf16(w1f4, xf[1], c1[0], 0, 0, 0);
        c1[1] = __builtin_amdgcn_mfma_f32_16x16x32_bf16(w1f5, xf[1], c1[1], 0, 0, 0);
        c1[2] = __builtin_amdgcn_mfma_f32_16x16x32_bf16(w1f6, xf[1], c1[2], 0, 0, 0);
        c1[3] = __builtin_amdgcn_mfma_f32_16x16x32_bf16(w1f7, xf[1], c1[3], 0, 0, 0);

        bf16x8 pf[2];
        #pragma unroll
        for (int s = 0; s < 2; ++s) {
            bf16x8 f;
            #pragma unroll
            for (int q = 0; q < 4; ++q) {
                f[q]     = f2bf(fast_tanh(c1[2 * s][q]));
                f[4 + q] = f2bf(fast_tanh(c1[2 * s + 1][q]));
            }
            pf[s] = f;
        }

        // layer 2
        f32x4 c2[4];
        #pragma unroll
        for (int tt = 0; tt < 4; ++tt) c2[tt] = bias2[tt];
        #pragma unroll
        for (int s = 0; s < 2; ++s)
            #pragma unroll
            for (int tt = 0; tt < 4; ++tt)
                c2[tt] = __builtin_amdgcn_mfma_f32_16x16x32_bf16(w2f[s][tt], pf[s], c2[tt], 0, 0, 0);

        bf16x8 qf[2];
        #pragma unroll
        for (int s = 0; s < 2; ++s) {
            bf16x8 f;
            #pragma unroll
            for (int q = 0; q < 4; ++q) {
                f[q]     = f2bf(fast_tanh(c2[2 * s][q]));
                f[4 + q] = f2bf(fast_tanh(c2[2 * s + 1][q]));
            }
            qf[s] = f;
        }

        // layer 3
        f32x4 c3 = {0.0f, 0.0f, 0.0f, 0.0f};
        c3 = __builtin_amdgcn_mfma_f32_16x16x32_bf16(w3f[0], qf[0], c3, 0, 0, 0);
        c3 = __builtin_amdgcn_mfma_f32_16x16x32_bf16(w3f[1], qf[1], c3, 0, 0, 0);

        if (g == 0) {
            const float mu = c3[0] + b30;
            const float al = c3[1] + b31;
            const float xn = x[(size_t)row * 64 + l + 1];   // f32 input
            const float zv = (xn - mu) * fast_exp(-al);
            zT[(62 - l) * BATCHN + row] = zv;
            aT[l * BATCHN + row] = al;
        }
    }
}

// 256 blocks x 64 rows: log_det + z col 0 + LDS transpose -> coalesced z_out.
__global__ __launch_bounds__(256) void maf_finish_kernel(
    const float* __restrict__ x,
    const float* __restrict__ ip,
    const float* __restrict__ zT,
    const float* __restrict__ aT,
    float* __restrict__ z_out,
    float* __restrict__ ld_out)
{
    __shared__ float tile[64][65];

    const int t = threadIdx.x;
    const int rb = blockIdx.x * 64;
    const float mu0 = ip[0];
    const float a0  = ip[1];
    const float e0  = fast_exp(-a0);

    // log_det: 4 lanes per row, shfl reduce
    {
        const int r = t >> 2, c = t & 3;
        const int row = rb + r;
        float s = 0.0f;
        for (int i = c; i < LN; i += 4) s += aT[(size_t)i * BATCHN + row];
        s += __shfl_xor(s, 1, 64);
        s += __shfl_xor(s, 2, 64);
        if (c == 0) ld_out[row] = -(s + a0);
    }

    // transpose 64 rows x 64 cols
    const int r = t & 63, cq = t >> 6;
    #pragma unroll
    for (int k = 0; k < 16; ++k) {
        const int c = cq * 16 + k;
        float v;
        if (c < 63) v = zT[(size_t)c * BATCHN + rb + r];
        else        v = (x[(size_t)(rb + r) * 64] - mu0) * e0;  // z col 0 -> cr 63
        tile[c][r] = v;
    }
    __syncthreads();
    #pragma unroll
    for (int i = 0; i < 16; ++i) {
        const int rr = cq * 16 + i;
        z_out[(size_t)(rb + rr) * 64 + r] = tile[r][rr];
    }
}

extern "C" void kernel_launch(void* const* d_in, const int* in_sizes, int n_in,
                              void* d_out, int out_size, void* d_ws, size_t ws_size,
                              hipStream_t stream) {
    const float* x  = (const float*)d_in[0];
    const float* ip = (const float*)d_in[1];
    const float* W1 = (const float*)d_in[2];
    const float* b1 = (const float*)d_in[3];
    const float* W2 = (const float*)d_in[4];
    const float* b2 = (const float*)d_in[5];
    const float* W3 = (const float*)d_in[6];
    const float* b3 = (const float*)d_in[7];

    float* z_out  = (float*)d_out;                     // [16384][64] (reversed cols)
    float* ld_out = z_out + (size_t)BATCHN * 64;       // [16384]

    // ws layout: Afrag [63*9216 u16 = 1.16MB] | zT 4.13MB | aT 4.13MB | xbf 2MB
    unsigned short* Afrag = (unsigned short*)d_ws;
    float* zT = (float*)((char*)d_ws + (size_t)LN * 9216 * 2);
    float* aT = zT + (size_t)LN * BATCHN;
    unsigned short* xbf = (unsigned short*)(aT + (size_t)LN * BATCHN);

    const size_t need_xbf = (size_t)LN * 9216 * 2 + (size_t)LN * BATCHN * 8 +
                            (size_t)BATCHN * 64 * 2;
    if (ws_size >= need_xbf) {
        prep_kernel<<<dim3(LN + BATCHN * 64 / 1024), dim3(256), 0, stream>>>(
            x, W1, b1, W2, W3, Afrag, xbf);
        maf_main_kernel<1><<<dim3(LN * 16), dim3(256), 0, stream>>>(
            x, xbf, Afrag, b2, b3, zT, aT);
    } else {
        prep_kernel<<<dim3(LN), dim3(256), 0, stream>>>(
            x, W1, b1, W2, W3, Afrag, xbf);
        maf_main_kernel<0><<<dim3(LN * 16), dim3(256), 0, stream>>>(
            x, xbf, Afrag, b2, b3, zT, aT);
    }
    maf_finish_kernel<<<dim3(BATCHN / 64), dim3(256), 0, stream>>>(
        x, ip, zT, aT, z_out, ld_out);
}

// Round 12
// 65.557 us; speedup vs baseline: 1.0170x; 1.0170x over previous
//
#include <hip/hip_runtime.h>

#define LN 63
#define BATCHN 16384

typedef __attribute__((ext_vector_type(8))) short bf16x8;   // 8 bf16 in 4 VGPRs
typedef __attribute__((ext_vector_type(4))) float f32x4;

__device__ __forceinline__ float fast_exp(float v) {
    return __builtin_amdgcn_exp2f(v * 1.4426950408889634f);
}
__device__ __forceinline__ float fast_tanh(float v) {
    float e = __builtin_amdgcn_exp2f(v * 2.8853900817779268f); // e^{2v}
    return 1.0f - 2.0f * __builtin_amdgcn_rcpf(e + 1.0f);
}
__device__ __forceinline__ short f2bf(float f) {
    __bf16 h = (__bf16)f;
    return __builtin_bit_cast(short, h);
}
__device__ __forceinline__ unsigned int pk2(float a, float b) {
    return (unsigned int)(unsigned short)f2bf(a) |
           ((unsigned int)(unsigned short)f2bf(b) << 16);
}

// kappa j-index for W2/W3 fragment element e (derived from R6's verified LDS
// reads): e<4 -> 32s+4g+e ; e>=4 -> 32s+16+4g+(e-4).
__device__ __forceinline__ int kappa_j(int s, int g, int e) {
    return (e < 4) ? (32 * s + 4 * g + e) : (32 * s + 16 + 4 * g + e - 4);
}

// Combined prep: blocks 0..62 write per-lane fragment-ordered bf16 weights
// into Afrag[l] (18432 B per l); blocks 63.. convert x -> xbf.  (R9-verified)
__global__ __launch_bounds__(256) void prep_kernel(
    const float* __restrict__ x,
    const float* __restrict__ W1, const float* __restrict__ b1,
    const float* __restrict__ W2, const float* __restrict__ W3,
    unsigned short* __restrict__ Afrag,
    unsigned short* __restrict__ xbf)
{
    const int t = threadIdx.x;
    const int b = blockIdx.x;
    if (b >= LN) {
        const int i = ((b - LN) * 256 + t) * 4;
        const float4 v = *reinterpret_cast<const float4*>(x + i);
        ushort4 o;
        o.x = (unsigned short)f2bf(v.x);
        o.y = (unsigned short)f2bf(v.y);
        o.z = (unsigned short)f2bf(v.z);
        o.w = (unsigned short)f2bf(v.w);
        *reinterpret_cast<ushort4*>(xbf + i) = o;
        return;
    }
    const int l = b;
    unsigned short* Af = Afrag + (size_t)l * 9216;

    // A1: 512 items (s,tt,lane), 2 per thread
    #pragma unroll
    for (int it = 0; it < 2; ++it) {
        const int item = t + it * 256;
        const int s = item >> 8, tt = (item >> 6) & 3, lane = item & 63;
        const int g = lane >> 4, mcol = lane & 15, h = 16 * tt + mcol;
        unsigned pk[4];
        #pragma unroll
        for (int ep = 0; ep < 4; ++ep) {
            float v[2];
            #pragma unroll
            for (int k = 0; k < 2; ++k) {
                const int e = 2 * ep + k;
                const int j = 32 * s + 8 * g + e;
                float val;
                if (j == 63)      val = b1[l * 64 + h];
                else if (j <= l)  val = W1[(l * LN + j) * 64 + h];
                else              val = 0.0f;
                v[k] = val;
            }
            pk[ep] = pk2(v[0], v[1]);
        }
        *reinterpret_cast<uint4*>(Af + ((size_t)item) * 8) =
            uint4{pk[0], pk[1], pk[2], pk[3]};
    }
    // A2: 512 items
    #pragma unroll
    for (int it = 0; it < 2; ++it) {
        const int item = t + it * 256;
        const int s = item >> 8, tt = (item >> 6) & 3, lane = item & 63;
        const int g = lane >> 4, mcol = lane & 15, h = 16 * tt + mcol;
        unsigned pk[4];
        #pragma unroll
        for (int ep = 0; ep < 4; ++ep) {
            float v[2];
            #pragma unroll
            for (int k = 0; k < 2; ++k) {
                const int e = 2 * ep + k;
                v[k] = W2[(l * 64 + kappa_j(s, g, e)) * 64 + h];
            }
            pk[ep] = pk2(v[0], v[1]);
        }
        *reinterpret_cast<uint4*>(Af + 4096 + ((size_t)item) * 8) =
            uint4{pk[0], pk[1], pk[2], pk[3]};
    }
    // A3: 128 items (s,lane)
    if (t < 128) {
        const int s = t >> 6, lane = t & 63;
        const int g = lane >> 4, mcol = lane & 15;
        unsigned pk[4] = {0u, 0u, 0u, 0u};
        if (mcol < 2) {
            #pragma unroll
            for (int ep = 0; ep < 4; ++ep) {
                float v[2];
                #pragma unroll
                for (int k = 0; k < 2; ++k) {
                    const int e = 2 * ep + k;
                    v[k] = W3[(l * 64 + kappa_j(s, g, e)) * 2 + mcol];
                }
                pk[ep] = pk2(v[0], v[1]);
            }
        }
        *reinterpret_cast<uint4*>(Af + 8192 + ((size_t)t) * 8) =
            uint4{pk[0], pk[1], pk[2], pk[3]};
    }
}

// Block = one l (0..62) x 1024 batch rows. Grid 63*16 = 1008. No LDS.
// R11: __launch_bounds__(256,4) caps TOTAL regs (VGPR+AGPR, unified file) at
// 128 -> 4 waves/SIMD. R10 lesson: arch-VGPR diet is irrelevant; occupancy is
// set by the total band the launch bound selects. Peak live at unroll-1 ~120:
// w2f/w3f/bias2 (56, AGPR-able) + w1f 32 + c1 16 + xf 8 + addr. No "+v" pins
// (remat disproven R9; allocator needs freedom under the cap).
// Register contents identical to R9 (verified absmax 0.0625).
template<int XBF>
__global__ __launch_bounds__(256, 4) void maf_main_kernel(
    const float* __restrict__ x,
    const unsigned short* __restrict__ xbf,
    const unsigned short* __restrict__ Afrag,
    const float* __restrict__ b2,
    const float* __restrict__ b3,
    float* __restrict__ zT,   // ws: [63][BATCH] row cr=62-l (z col l+1 reversed)
    float* __restrict__ aT)   // ws: [63][BATCH] alpha col l+1
{
    const int t = threadIdx.x;
    const int bid = blockIdx.x;
    const int l = bid % LN;                 // block-uniform
    const int rowBase = (bid / LN) * 1024;

    const int lane = t & 63;
    const int w = t >> 6;
    const int g = lane >> 4;
    const int mcol = lane & 15;

    // ---------------- persistent A-fragments: W2, W3, bias2 ----------------
    const unsigned short* Af = Afrag + (size_t)l * 9216;
    bf16x8 w2f[2][4], w3f[2];
    #pragma unroll
    for (int s = 0; s < 2; ++s) {
        #pragma unroll
        for (int tt = 0; tt < 4; ++tt)
            w2f[s][tt] = *reinterpret_cast<const bf16x8*>(Af + 4096 + ((s * 4 + tt) * 64 + lane) * 8);
        w3f[s] = *reinterpret_cast<const bf16x8*>(Af + 8192 + (s * 64 + lane) * 8);
    }
    f32x4 bias2[4];
    #pragma unroll
    for (int tt = 0; tt < 4; ++tt) {
        const float4 v2 = *reinterpret_cast<const float4*>(&b2[l * 64 + 16 * tt + 4 * g]);
        bias2[tt] = f32x4{v2.x, v2.y, v2.z, v2.w};
    }
    const float b30 = b3[l * 2 + 0];
    const float b31 = b3[l * 2 + 1];
    const short one_bf = (short)0x3F80;   // bf16(1.0)

    // ---------------- 16 groups of 16 rows per wave ----------------
    #pragma unroll 1
    for (int grp = 0; grp < 16; ++grp) {
        const int row = rowBase + w * 256 + grp * 16 + mcol;

        // w1f: 8 x 16B, same addr every grp -> L1-resident (compiler may keep
        // or reload under the 128-reg cap; both acceptable at 4 waves TLP)
        bf16x8 w1f[2][4];
        #pragma unroll
        for (int s = 0; s < 2; ++s)
            #pragma unroll
            for (int tt = 0; tt < 4; ++tt)
                w1f[s][tt] = *reinterpret_cast<const bf16x8*>(Af + ((s * 4 + tt) * 64 + lane) * 8);

        bf16x8 xf[2];
        if constexpr (XBF) {
            xf[0] = *reinterpret_cast<const bf16x8*>(xbf + (size_t)row * 64 + 8 * g);
            xf[1] = *reinterpret_cast<const bf16x8*>(xbf + (size_t)row * 64 + 32 + 8 * g);
        } else {
            const float* xr = x + (size_t)row * 64;
            #pragma unroll
            for (int s = 0; s < 2; ++s) {
                const float4 a = *reinterpret_cast<const float4*>(xr + 32 * s + 8 * g);
                const float4 b = *reinterpret_cast<const float4*>(xr + 32 * s + 8 * g + 4);
                bf16x8 f;
                f[0] = f2bf(a.x); f[1] = f2bf(a.y); f[2] = f2bf(a.z); f[3] = f2bf(a.w);
                f[4] = f2bf(b.x); f[5] = f2bf(b.y); f[6] = f2bf(b.z); f[7] = f2bf(b.w);
                xf[s] = f;
            }
        }
        // k-slot 63 pairs with the b1 row staged in A1: force to 1.0
        if (g == 3) xf[1][7] = one_bf;

        // layer 1 (bias via k-slot 63)
        f32x4 c1[4];
        #pragma unroll
        for (int tt = 0; tt < 4; ++tt) c1[tt] = f32x4{0.0f, 0.0f, 0.0f, 0.0f};
        #pragma unroll
        for (int s = 0; s < 2; ++s)
            #pragma unroll
            for (int tt = 0; tt < 4; ++tt)
                c1[tt] = __builtin_amdgcn_mfma_f32_16x16x32_bf16(w1f[s][tt], xf[s], c1[tt], 0, 0, 0);

        bf16x8 pf[2];
        #pragma unroll
        for (int s = 0; s < 2; ++s) {
            bf16x8 f;
            #pragma unroll
            for (int q = 0; q < 4; ++q) {
                f[q]     = f2bf(fast_tanh(c1[2 * s][q]));
                f[4 + q] = f2bf(fast_tanh(c1[2 * s + 1][q]));
            }
            pf[s] = f;
        }

        // layer 2
        f32x4 c2[4];
        #pragma unroll
        for (int tt = 0; tt < 4; ++tt) c2[tt] = bias2[tt];
        #pragma unroll
        for (int s = 0; s < 2; ++s)
            #pragma unroll
            for (int tt = 0; tt < 4; ++tt)
                c2[tt] = __builtin_amdgcn_mfma_f32_16x16x32_bf16(w2f[s][tt], pf[s], c2[tt], 0, 0, 0);

        bf16x8 qf[2];
        #pragma unroll
        for (int s = 0; s < 2; ++s) {
            bf16x8 f;
            #pragma unroll
            for (int q = 0; q < 4; ++q) {
                f[q]     = f2bf(fast_tanh(c2[2 * s][q]));
                f[4 + q] = f2bf(fast_tanh(c2[2 * s + 1][q]));
            }
            qf[s] = f;
        }

        // layer 3
        f32x4 c3 = {0.0f, 0.0f, 0.0f, 0.0f};
        c3 = __builtin_amdgcn_mfma_f32_16x16x32_bf16(w3f[0], qf[0], c3, 0, 0, 0);
        c3 = __builtin_amdgcn_mfma_f32_16x16x32_bf16(w3f[1], qf[1], c3, 0, 0, 0);

        if (g == 0) {
            const float mu = c3[0] + b30;
            const float al = c3[1] + b31;
            const float xn = x[(size_t)row * 64 + l + 1];   // f32 input
            const float zv = (xn - mu) * fast_exp(-al);
            zT[(62 - l) * BATCHN + row] = zv;
            aT[l * BATCHN + row] = al;
        }
    }
}

// 256 blocks x 64 rows: log_det + z col 0 + LDS transpose -> coalesced z_out.
__global__ __launch_bounds__(256) void maf_finish_kernel(
    const float* __restrict__ x,
    const float* __restrict__ ip,
    const float* __restrict__ zT,
    const float* __restrict__ aT,
    float* __restrict__ z_out,
    float* __restrict__ ld_out)
{
    __shared__ float tile[64][65];

    const int t = threadIdx.x;
    const int rb = blockIdx.x * 64;
    const float mu0 = ip[0];
    const float a0  = ip[1];
    const float e0  = fast_exp(-a0);

    // log_det: 4 lanes per row, shfl reduce
    {
        const int r = t >> 2, c = t & 3;
        const int row = rb + r;
        float s = 0.0f;
        for (int i = c; i < LN; i += 4) s += aT[(size_t)i * BATCHN + row];
        s += __shfl_xor(s, 1, 64);
        s += __shfl_xor(s, 2, 64);
        if (c == 0) ld_out[row] = -(s + a0);
    }

    // transpose 64 rows x 64 cols
    const int r = t & 63, cq = t >> 6;
    #pragma unroll
    for (int k = 0; k < 16; ++k) {
        const int c = cq * 16 + k;
        float v;
        if (c < 63) v = zT[(size_t)c * BATCHN + rb + r];
        else        v = (x[(size_t)(rb + r) * 64] - mu0) * e0;  // z col 0 -> cr 63
        tile[c][r] = v;
    }
    __syncthreads();
    #pragma unroll
    for (int i = 0; i < 16; ++i) {
        const int rr = cq * 16 + i;
        z_out[(size_t)(rb + rr) * 64 + r] = tile[r][rr];
    }
}

extern "C" void kernel_launch(void* const* d_in, const int* in_sizes, int n_in,
                              void* d_out, int out_size, void* d_ws, size_t ws_size,
                              hipStream_t stream) {
    const float* x  = (const float*)d_in[0];
    const float* ip = (const float*)d_in[1];
    const float* W1 = (const float*)d_in[2];
    const float* b1 = (const float*)d_in[3];
    const float* W2 = (const float*)d_in[4];
    const float* b2 = (const float*)d_in[5];
    const float* W3 = (const float*)d_in[6];
    const float* b3 = (const float*)d_in[7];

    float* z_out  = (float*)d_out;                     // [16384][64] (reversed cols)
    float* ld_out = z_out + (size_t)BATCHN * 64;       // [16384]

    // ws layout: Afrag [63*9216 u16 = 1.16MB] | zT 4.13MB | aT 4.13MB | xbf 2MB
    unsigned short* Afrag = (unsigned short*)d_ws;
    float* zT = (float*)((char*)d_ws + (size_t)LN * 9216 * 2);
    float* aT = zT + (size_t)LN * BATCHN;
    unsigned short* xbf = (unsigned short*)(aT + (size_t)LN * BATCHN);

    const size_t need_xbf = (size_t)LN * 9216 * 2 + (size_t)LN * BATCHN * 8 +
                            (size_t)BATCHN * 64 * 2;
    if (ws_size >= need_xbf) {
        prep_kernel<<<dim3(LN + BATCHN * 64 / 1024), dim3(256), 0, stream>>>(
            x, W1, b1, W2, W3, Afrag, xbf);
        maf_main_kernel<1><<<dim3(LN * 16), dim3(256), 0, stream>>>(
            x, xbf, Afrag, b2, b3, zT, aT);
    } else {
        prep_kernel<<<dim3(LN), dim3(256), 0, stream>>>(
            x, W1, b1, W2, W3, Afrag, xbf);
        maf_main_kernel<0><<<dim3(LN * 16), dim3(256), 0, stream>>>(
            x, xbf, Afrag, b2, b3, zT, aT);
    }
    maf_finish_kernel<<<dim3(BATCHN / 64), dim3(256), 0, stream>>>(
        x, ip, zT, aT, z_out, ld_out);
}